// Round 9
// baseline (769.302 us; speedup 1.0000x reference)
//
#include <hip/hip_runtime.h>
#include <hip/hip_bf16.h>

#define IN_DIM 1024
#define H_DIM  1024
#define C_DIM  16
#define B_DIM  4096
#define K_DIM  2048      // IN + H
#define N_DIM  32768     // C * 2H
#define M_DIM  4096      // B
#define NT     32        // K_DIM / 64 K-steps

typedef __attribute__((ext_vector_type(8))) short short8;
typedef __attribute__((ext_vector_type(4))) float f32x4;

__device__ __forceinline__ unsigned short f2bf_rne(float f) {
  union { float f; unsigned u; } a; a.f = f;
  unsigned r = a.u + 0x7FFFu + ((a.u >> 16) & 1u);
  return (unsigned short)(r >> 16);
}

// Pack rows: out[r][0:1024] = bf16(xs[r][:]), out[r][1024:2048] = bf16(hs[r][:])
__global__ void convert_pack_kernel(const float* __restrict__ xs,
                                    const float* __restrict__ hs,
                                    unsigned short* __restrict__ out,
                                    int rows) {
  long total = (long)rows * (K_DIM / 8);
  for (long i = blockIdx.x * (long)blockDim.x + threadIdx.x; i < total;
       i += (long)gridDim.x * blockDim.x) {
    long e = i * 8;
    int r = (int)(e >> 11);
    int k = (int)(e & 2047);
    const float* src = (k < IN_DIM) ? (xs + (long)r * IN_DIM + k)
                                    : (hs + (long)r * H_DIM + (k - IN_DIM));
    float4 v0 = *(const float4*)(src);
    float4 v1 = *(const float4*)(src + 4);
    union { unsigned short u[8]; short8 s; } p;
    p.u[0] = f2bf_rne(v0.x); p.u[1] = f2bf_rne(v0.y);
    p.u[2] = f2bf_rne(v0.z); p.u[3] = f2bf_rne(v0.w);
    p.u[4] = f2bf_rne(v1.x); p.u[5] = f2bf_rne(v1.y);
    p.u[6] = f2bf_rne(v1.z); p.u[7] = f2bf_rne(v1.w);
    *(short8*)(out + e) = p.s;
  }
}

// Opaque LDS-DMA: compiler's waitcnt pass sees no LDS write here, so no
// conservative vmcnt(0) is inserted before IR ds_reads; our counted vmcnt
// is the only VMEM wait. HW writes lane i at m0 + i*16 (lane-linear dest).
__device__ __forceinline__ void dma16(const short* g, int ldsOff) {
  asm volatile("s_mov_b32 m0, %1\n\t"
               "global_load_lds_dwordx4 %0, off"
               :: "v"(g), "s"(ldsOff) : "memory");
}

// C = A(M x K) * Bt(N x K)^T + bias, fused sigmoid/tanh epilogue.
// m201 8-phase template: 256x256 tile, BK=64, 8 waves (2Mx4N), wave tile
// 128x64, parity-fixed double buffers (even tile->buf0). Per phase:
//   { ds_read this phase's frags; stage; [vmcnt(4) @ph3/ph7]; s_barrier;
//     setprio(1); 16 MFMA; setprio(0); s_barrier; }
//
// QUARTER GROUPING (the round-8 bug): wave wr reads A rows wr*128+...:
//   A-lo (mi0-3) = quarters {q0, q128};  A-hi (mi4-7) = {q64, q192}.
// Stage slots MUST use this pairing so no phase writes a quarter it reads:
//   ph0: A-hi{q64,q192}(t1)+B-h1{q128,q192}(t1) -> buf1
//   ph2: A-lo{q0,q128}(t2) -> buf0     ph3: B-h0{q0,q64}(t2) -> buf0
//   ph4: A-hi{q64,q192}(t2)+B-h1(t2) -> buf0
//   ph6: A-lo{q0,q128}(t3) -> buf1     ph7: B-h0(t3) -> buf1
// FIFO: entry=4, peak=12; end-ph3 vmcnt(4) retires all of t1 (read ph4-7);
// end-ph7 vmcnt(4) retires all of t2 (read next ph0-3). Never drained.
__global__ void __launch_bounds__(512, 2)
gemm_act_kernel(const short* __restrict__ A,   // [M][K] bf16 bits
                const short* __restrict__ Bt,  // [N][K] bf16 bits
                const float* __restrict__ bias,// [N]
                float* __restrict__ out) {
  extern __shared__ short lds[];
  // shorts: A0=0, A1=16384, B0=32768, B1=49152
  // bytes : A0=0, A1=32768, B0=65536, B1=98304

  // bijective XCD swizzle (nwg = 2048, divisible by 8); m-fastest tiling
  int cpx = (int)gridDim.x >> 3;
  int wg  = ((int)blockIdx.x & 7) * cpx + ((int)blockIdx.x >> 3);
  int mt = wg & 15;           // M/256 = 16 tiles
  int nt = wg >> 4;           // N/256 = 128 tiles
  int m0 = mt * 256;
  int n0 = nt * 256;

  const int tid  = (int)threadIdx.x;
  const int lane = tid & 63;
  const int wid  = tid >> 6;
  const int wr   = wid >> 2;   // wave rows wr*128
  const int wc   = wid & 3;    // wave cols wc*64

  // ---- epilogue constants FIRST (only IR vmem loads, before any DMA) ----
  const int crow = (lane >> 4) * 4;
  const int ccol = lane & 15;
  const long HALF = (long)B_DIM * C_DIM * H_DIM;  // 67108864
  float bia[4]; int cg[4], og[4];
#pragma unroll
  for (int ni = 0; ni < 4; ++ni) {
    int gn = n0 + wc * 64 + ni * 16 + ccol;
    bia[ni] = bias[gn];
    cg[ni] = gn >> 11;
    og[ni] = gn & 2047;
  }

  // ---- staging (T2: swizzled global source, lane-linear LDS dest) ----
  const int srow = tid >> 3;                 // 0..63 row within quarter
  const int sc   = (tid & 7) ^ (srow & 7);   // swizzled src 16B chunk
  const short* Abase = A  + (long)(m0 + srow) * K_DIM + sc * 8;
  const short* Bbase = Bt + (long)(n0 + srow) * K_DIM + sc * 8;
  const int wb = __builtin_amdgcn_readfirstlane((tid >> 6) * 1024); // wave LDS base (bytes)

  auto stA = [&](int kt, int r0, int bufByte) {   // one 64-row quarter
    dma16(Abase + (long)r0 * K_DIM + kt * 64, bufByte + r0 * 128 + wb);
  };
  auto stB = [&](int kt, int r0, int bufByte) {
    dma16(Bbase + (long)r0 * K_DIM + kt * 64, 65536 + bufByte + r0 * 128 + wb);
  };

  // ---- fragment LDS base offsets (shorts); mi adds mi*1024 (immediate) ----
  const int fr = lane & 15;
  const int g8 = lane >> 4;
  int aoff[2], boff[2];
#pragma unroll
  for (int kk = 0; kk < 2; ++kk) {
    aoff[kk] = (wr * 128 + fr) * 64 + (((kk * 4 + g8) ^ (fr & 7)) << 3);
    boff[kk] = (wc * 64  + fr) * 64 + (((kk * 4 + g8) ^ (fr & 7)) << 3);
  }
  auto rdA = [&](int baseS, int mi, int kk) {
    return *(const short8*)(lds + baseS + aoff[kk] + mi * 1024);
  };
  auto rdB = [&](int baseS, int ni, int kk) {
    return *(const short8*)(lds + baseS + boff[kk] + ni * 1024);
  };

  f32x4 acc[8][4] = {};
  auto mfma4 = [&](short8 (&a)[4], short8 (&b)[4], int mb) {
#pragma unroll
    for (int i = 0; i < 4; ++i)
#pragma unroll
      for (int j = 0; j < 4; ++j)
        acc[mb + i][j] = __builtin_amdgcn_mfma_f32_16x16x32_bf16(a[i], b[j], acc[mb + i][j], 0, 0, 0);
  };

  // ---- prologue: tile0 full (8 loads) + {A-lo{q0,q128}, B-h0}(1) ----
  stA(0, 0, 0);      stA(0, 64, 0);      stA(0, 128, 0);      stA(0, 192, 0);
  stB(0, 0, 0);      stB(0, 64, 0);      stB(0, 128, 0);      stB(0, 192, 0);
  stA(1, 0, 32768);  stA(1, 128, 32768);
  stB(1, 0, 32768);  stB(1, 64, 32768);
  asm volatile("s_waitcnt vmcnt(4)" ::: "memory");  // retires tile0; 4 in flight
  __builtin_amdgcn_s_barrier();

  for (int t = 0; t < NT; t += 2) {
    const int t1 = t + 1;                         // always < NT
    const int t2 = (t + 2 < NT) ? t + 2 : NT - 1; // clamped tail: rewrites
    const int t3 = (t + 3 < NT) ? t + 3 : NT - 1; // identical bytes (safe)
    short8 av[4], bv0[4], bv1[4];
    // ---- ph0: reads A0.lo.k0 + B0.k0; stage A-hi{q64,q192}+B-h1(t1)->buf1 --
#pragma unroll
    for (int i = 0; i < 4; ++i) av[i] = rdA(0, i, 0);
#pragma unroll
    for (int j = 0; j < 4; ++j) bv0[j] = rdB(32768, j, 0);
    stA(t1, 64, 32768); stA(t1, 192, 32768);
    stB(t1, 128, 32768); stB(t1, 192, 32768);
    __builtin_amdgcn_s_barrier();
    __builtin_amdgcn_s_setprio(1);
    mfma4(av, bv0, 0);
    __builtin_amdgcn_s_setprio(0);
    __builtin_amdgcn_s_barrier();
    // ---- ph1: reads A0.lo.k1 + B0.k1; no stage ----
#pragma unroll
    for (int i = 0; i < 4; ++i) av[i] = rdA(0, i, 1);
#pragma unroll
    for (int j = 0; j < 4; ++j) bv1[j] = rdB(32768, j, 1);
    __builtin_amdgcn_s_barrier();
    __builtin_amdgcn_s_setprio(1);
    mfma4(av, bv1, 0);
    __builtin_amdgcn_s_setprio(0);
    __builtin_amdgcn_s_barrier();
    // ---- ph2: reads A0.hi.k0 {q64,q192}; stage A-lo{q0,q128}(t2)->buf0 ----
#pragma unroll
    for (int i = 0; i < 4; ++i) av[i] = rdA(0, 4 + i, 0);
    stA(t2, 0, 0); stA(t2, 128, 0);
    __builtin_amdgcn_s_barrier();
    __builtin_amdgcn_s_setprio(1);
    mfma4(av, bv0, 4);
    __builtin_amdgcn_s_setprio(0);
    __builtin_amdgcn_s_barrier();
    // ---- ph3: reads A0.hi.k1; stage B-h0(t2)->buf0; vmcnt(4) ----
#pragma unroll
    for (int i = 0; i < 4; ++i) av[i] = rdA(0, 4 + i, 1);
    stB(t2, 0, 0); stB(t2, 64, 0);
    asm volatile("s_waitcnt vmcnt(4)" ::: "memory");  // retires all of t1
    __builtin_amdgcn_s_barrier();
    __builtin_amdgcn_s_setprio(1);
    mfma4(av, bv1, 4);
    __builtin_amdgcn_s_setprio(0);
    __builtin_amdgcn_s_barrier();
    // ---- ph4: reads A1.lo.k0 + B1.k0; stage A-hi{q64,q192}+B-h1(t2)->buf0 --
#pragma unroll
    for (int i = 0; i < 4; ++i) av[i] = rdA(16384, i, 0);
#pragma unroll
    for (int j = 0; j < 4; ++j) bv0[j] = rdB(49152, j, 0);
    stA(t2, 64, 0); stA(t2, 192, 0);
    stB(t2, 128, 0); stB(t2, 192, 0);
    __builtin_amdgcn_s_barrier();
    __builtin_amdgcn_s_setprio(1);
    mfma4(av, bv0, 0);
    __builtin_amdgcn_s_setprio(0);
    __builtin_amdgcn_s_barrier();
    // ---- ph5: reads A1.lo.k1 + B1.k1; no stage ----
#pragma unroll
    for (int i = 0; i < 4; ++i) av[i] = rdA(16384, i, 1);
#pragma unroll
    for (int j = 0; j < 4; ++j) bv1[j] = rdB(49152, j, 1);
    __builtin_amdgcn_s_barrier();
    __builtin_amdgcn_s_setprio(1);
    mfma4(av, bv1, 0);
    __builtin_amdgcn_s_setprio(0);
    __builtin_amdgcn_s_barrier();
    // ---- ph6: reads A1.hi.k0 {q64,q192}; stage A-lo{q0,q128}(t3)->buf1 ----
#pragma unroll
    for (int i = 0; i < 4; ++i) av[i] = rdA(16384, 4 + i, 0);
    stA(t3, 0, 32768); stA(t3, 128, 32768);
    __builtin_amdgcn_s_barrier();
    __builtin_amdgcn_s_setprio(1);
    mfma4(av, bv0, 4);
    __builtin_amdgcn_s_setprio(0);
    __builtin_amdgcn_s_barrier();
    // ---- ph7: reads A1.hi.k1; stage B-h0(t3)->buf1; vmcnt(4) ----
#pragma unroll
    for (int i = 0; i < 4; ++i) av[i] = rdA(16384, 4 + i, 1);
    stB(t3, 0, 32768); stB(t3, 64, 32768);
    asm volatile("s_waitcnt vmcnt(4)" ::: "memory");  // retires all of t2
    __builtin_amdgcn_s_barrier();
    __builtin_amdgcn_s_setprio(1);
    mfma4(av, bv1, 4);
    __builtin_amdgcn_s_setprio(0);
    __builtin_amdgcn_s_barrier();
  }
  asm volatile("s_waitcnt vmcnt(0)" ::: "memory");

  // ---- epilogue: C/D layout col=lane&15, row=(lane>>4)*4+j ----
#pragma unroll
  for (int mi = 0; mi < 8; ++mi) {
    int gb0 = m0 + wr * 128 + mi * 16 + crow;
#pragma unroll
    for (int ni = 0; ni < 4; ++ni) {
      int c = cg[ni], o = og[ni];
#pragma unroll
      for (int j = 0; j < 4; ++j) {
        float v = acc[mi][ni][j] + bia[ni];
        long b = gb0 + j;
        if (o < H_DIM) {  // input_gate = sigmoid -> output 1 (second half)
          float r = 1.0f / (1.0f + __expf(-v));
          __builtin_nontemporal_store(r, &out[HALF + (b * C_DIM + c) * H_DIM + o]);
        } else {          // cell_input = tanh -> output 0 (first half)
          float av2 = fabsf(v);
          float e = __expf(-2.0f * av2);
          float r = (1.0f - e) / (1.0f + e);
          r = (v < 0.0f) ? -r : r;
          __builtin_nontemporal_store(r, &out[(b * C_DIM + c) * H_DIM + (o - H_DIM)]);
        }
      }
    }
  }
}

// Correctness-only fallback if workspace is too small for bf16 staging.
__global__ void fallback_kernel(const float* __restrict__ x,
                                const float* __restrict__ h,
                                const float* __restrict__ Wx,
                                const float* __restrict__ bx,
                                const float* __restrict__ Wh,
                                float* __restrict__ out) {
  int b = blockIdx.x;
  int c = blockIdx.y;
  __shared__ float lx[IN_DIM], lh[H_DIM];
  for (int i = threadIdx.x; i < IN_DIM; i += blockDim.x) {
    lx[i] = x[(long)b * IN_DIM + i];
    lh[i] = h[(long)b * H_DIM + i];
  }
  __syncthreads();
  const long HALF = (long)B_DIM * C_DIM * H_DIM;
  for (int o = threadIdx.x; o < 2 * H_DIM; o += blockDim.x) {
    const float* wx = Wx + ((long)c * 2 * H_DIM + o) * IN_DIM;
    const float* wh = Wh + ((long)c * 2 * H_DIM + o) * H_DIM;
    float acc = bx[c * 2 * H_DIM + o];
    for (int k = 0; k < IN_DIM; ++k) acc += lx[k] * wx[k];
    for (int k = 0; k < H_DIM; ++k) acc += lh[k] * wh[k];
    if (o < H_DIM) {
      out[HALF + ((long)b * C_DIM + c) * H_DIM + o] = 1.0f / (1.0f + __expf(-acc));
    } else {
      float av = fabsf(acc);
      float t = __expf(-2.0f * av);
      float r = (1.0f - t) / (1.0f + t);
      out[((long)b * C_DIM + c) * H_DIM + (o - H_DIM)] = (acc < 0.0f) ? -r : r;
    }
  }
}

extern "C" void kernel_launch(void* const* d_in, const int* in_sizes, int n_in,
                              void* d_out, int out_size, void* d_ws, size_t ws_size,
                              hipStream_t stream) {
  const float* x  = (const float*)d_in[0];   // (B, IN)
  const float* h  = (const float*)d_in[1];   // (B, H)
  const float* Wx = (const float*)d_in[2];   // (C, 2H, IN)
  const float* bx = (const float*)d_in[3];   // (C, 2H)
  const float* Wh = (const float*)d_in[4];   // (C, 2H, H)
  float* out = (float*)d_out;                // [cell_input | input_gate], each (B,C,H)

  const size_t needA = (size_t)M_DIM * K_DIM * sizeof(short);  // 16 MiB
  const size_t needB = (size_t)N_DIM * K_DIM * sizeof(short);  // 128 MiB
  if (ws_size < needA + needB) {
    dim3 g(B_DIM, C_DIM);
    fallback_kernel<<<g, 256, 0, stream>>>(x, h, Wx, bx, Wh, out);
    return;
  }

  unsigned short* Abf = (unsigned short*)d_ws;
  unsigned short* Bbf = (unsigned short*)((char*)d_ws + needA);

  convert_pack_kernel<<<2048, 256, 0, stream>>>(x, h, Abf, M_DIM);
  convert_pack_kernel<<<4096, 256, 0, stream>>>(Wx, Wh, Bbf, N_DIM);

  (void)hipFuncSetAttribute((const void*)gemm_act_kernel,
                            hipFuncAttributeMaxDynamicSharedMemorySize, 131072);
  gemm_act_kernel<<<2048, 512, 131072, stream>>>((const short*)Abf, (const short*)Bbf,
                                                 bx, out);
}